// Round 2
// baseline (492.657 us; speedup 1.0000x reference)
//
// SelfAttentionWide (B=4, T=1024, E=512, H=8 wide heads) — MI355X gfx950
// Round 2: fp32 inputs / fp32 output (NaN in R1 proved dtype mismatch).
// Pre-pass converts x,w_k,w_q,w_v,w_u to bf16 in ws; MFMA pipeline unchanged.
// Layouts: Q/K/V/O in (b,h,t,e) bf16; scores S fp32 per (b,h); P bf16 in-place over S (lda=2048).
#include <hip/hip_runtime.h>
#include <stdint.h>

typedef unsigned short u16;
typedef unsigned int u32;
typedef __bf16 bf16_t;
typedef __attribute__((ext_vector_type(8))) bf16_t bf16x8;
typedef __attribute__((ext_vector_type(4))) float floatx4;

__device__ __forceinline__ u16 f2b(float f) {
  u32 u = __float_as_uint(f);
  return (u16)((u + 0x7fffu + ((u >> 16) & 1u)) >> 16);
}

// async 16B/lane global->LDS; LDS dest is wave-uniform base + lane*16
__device__ __forceinline__ void gload_lds16(const u16* g, u16* l) {
  __builtin_amdgcn_global_load_lds(
      (const __attribute__((address_space(1))) u32*)g,
      (__attribute__((address_space(3))) u32*)l, 16, 0, 0);
}

// fp32 -> bf16 elementwise, 4 elems/thread
__global__ __launch_bounds__(256) void cvt_kernel(const float* __restrict__ s,
                                                  u16* __restrict__ d, int n4) {
  const int i = blockIdx.x * 256 + threadIdx.x;
  if (i < n4) {
    const float4 v = ((const float4*)s)[i];
    ushort4 o;
    o.x = f2b(v.x); o.y = f2b(v.y); o.z = f2b(v.z); o.w = f2b(v.w);
    ((ushort4*)d)[i] = o;
  }
}

enum { A_PLAIN = 0, A_HEADBLK = 1 };   // HEADBLK: A is O in (b,h,t,e), logical (r=(b,t), k=(h,e))
enum { B_PLAIN = 0, B_TRANS = 1 };     // TRANS: B global is (k,n) row-major (V), stage transposed
enum { C_BF16_PLAIN = 0, C_BF16_BHTE = 1, C_F32_PLAIN = 2 };

// C[M x N] = A[M x K] @ B[N x K]^T  (bf16 in, fp32 acc), tile 128x128x32,
// 256 thr = 4 waves (2x2), wave = 4x4 of 16x16x32 MFMA.
template <int AMODE, int BMODE, int CMODE, bool CAUSAL_SKIP, bool PV_KLIM, bool HAS_BIAS>
__global__ __launch_bounds__(256, 2) void gemm_kernel(
    const u16* __restrict__ A, int lda, long a_zstride,
    const u16* __restrict__ B, int ldb, long b_zstride,
    void* __restrict__ C, int ldc, long c_zstride,
    const float* __restrict__ bias, int K, float scale) {
  const int bn = blockIdx.x, bm = blockIdx.y, bz = blockIdx.z;
  if (CAUSAL_SKIP && bn > bm) return;

  int kTiles = K >> 5;
  if (PV_KLIM) kTiles = (bm + 1) * 4;  // rows q in [bm*128,+128) only need k < (bm+1)*128

  const u16* Ab = A + (long)bz * a_zstride;
  const u16* Bb = B + (long)bz * b_zstride;

  constexpr int BSTR = (BMODE == B_TRANS) ? 40 : 32;  // pad to 40 (80B, 16B-mult) vs conflicts
  __shared__ u16 sA[128 * 32];
  __shared__ u16 sB[128 * BSTR];

  const int tid = threadIdx.x;
  const int wid = tid >> 6;
  const int lane = tid & 63;
  const int lrow = lane & 15;
  const int quad = lane >> 4;
  const int wm = wid >> 1, wn = wid & 1;
  const int m0 = bm * 128, n0 = bn * 128;

  const int sgr = lane >> 2;        // staging row within 16-row chunk
  const int sgc = (lane & 3) << 3;  // staging col (8 bf16 = 16B)

  floatx4 acc[4][4];
#pragma unroll
  for (int i = 0; i < 4; ++i)
#pragma unroll
    for (int j = 0; j < 4; ++j) acc[i][j] = (floatx4)0.0f;

  for (int kt = 0; kt < kTiles; ++kt) {
    const int k0 = kt << 5;
    // ---- stage A tile (async, 16B/lane): wave wid covers rows [wid*32, wid*32+32)
#pragma unroll
    for (int j = 0; j < 2; ++j) {
      const int r = wid * 32 + j * 16 + sgr;
      const u16* g;
      if constexpr (AMODE == A_PLAIN) {
        g = Ab + (long)(m0 + r) * lda + (k0 + sgc);
      } else {
        const int rg = m0 + r, kg = k0 + sgc;
        g = Ab + (long)((rg >> 10) * 8 + (kg >> 9)) * 524288 +
            (long)(rg & 1023) * 512 + (kg & 511);
      }
      gload_lds16(g, &sA[(wid * 32 + j * 16) * 32]);
    }
    // ---- stage B tile
    if constexpr (BMODE == B_PLAIN) {
#pragma unroll
      for (int j = 0; j < 2; ++j) {
        const int r = wid * 32 + j * 16 + sgr;
        const u16* g = Bb + (long)(n0 + r) * ldb + (k0 + sgc);
        gload_lds16(g, &sB[(wid * 32 + j * 16) * 32]);
      }
    } else {
      // transpose-stage V chunk: global (k0+tr, n0+te..te+15) -> sB[n][k]
      const int tr = tid & 31, te = (tid >> 5) << 4;
      const u16* g = Bb + (long)(k0 + tr) * ldb + (n0 + te);
      union { uint4 v[2]; u16 s[16]; } tmp;
      tmp.v[0] = *(const uint4*)g;
      tmp.v[1] = *(const uint4*)(g + 8);
#pragma unroll
      for (int i = 0; i < 16; ++i) sB[(te + i) * BSTR + tr] = tmp.s[i];
    }
    __syncthreads();

    bf16x8 af[4], bfr[4];
#pragma unroll
    for (int i = 0; i < 4; ++i)
      af[i] = *(const bf16x8*)&sA[(wm * 64 + i * 16 + lrow) * 32 + (quad << 3)];
#pragma unroll
    for (int i = 0; i < 4; ++i)
      bfr[i] = *(const bf16x8*)&sB[(wn * 64 + i * 16 + lrow) * BSTR + (quad << 3)];
#pragma unroll
    for (int mi = 0; mi < 4; ++mi)
#pragma unroll
      for (int ni = 0; ni < 4; ++ni)
        acc[mi][ni] = __builtin_amdgcn_mfma_f32_16x16x32_bf16(af[mi], bfr[ni], acc[mi][ni], 0, 0, 0);
    __syncthreads();
  }

  // ---- epilogue: D[row=(quad*4+r)][col=lrow] per 16x16 tile (m89-verified layout)
#pragma unroll
  for (int mi = 0; mi < 4; ++mi) {
#pragma unroll
    for (int ni = 0; ni < 4; ++ni) {
      const int cg = n0 + wn * 64 + ni * 16 + lrow;
      float bv = 0.0f;
      if constexpr (HAS_BIAS) bv = bias[cg];
#pragma unroll
      for (int r = 0; r < 4; ++r) {
        const int rg = m0 + wm * 64 + mi * 16 + quad * 4 + r;
        const float val = acc[mi][ni][r] * scale + bv;
        if constexpr (CMODE == C_F32_PLAIN) {
          ((float*)C)[(long)bz * c_zstride + (long)rg * ldc + cg] = val;
        } else if constexpr (CMODE == C_BF16_PLAIN) {
          ((u16*)C)[(long)bz * c_zstride + (long)rg * ldc + cg] = f2b(val);
        } else {  // C_BF16_BHTE: (r=(b,t), c=(h,e)) -> (b,h,t,e)
          const long idx = (long)((rg >> 10) * 8 + (cg >> 9)) * 524288 +
                           (long)(rg & 1023) * 512 + (cg & 511);
          ((u16*)C)[idx] = f2b(val);
        }
      }
    }
  }
}

// causal row softmax over S fp32 row q (cols 0..q), write P bf16 in place (lda=2048),
// zero-fill P cols q+1 .. round_up_128(q+1) so the PV GEMM can read full k-tiles.
__global__ __launch_bounds__(256) void softmax_kernel(float* __restrict__ S) {
  const int q = blockIdx.x;
  const long zoff = (long)blockIdx.y * 1048576;
  const float* Srow = S + zoff + (long)q * 1024;
  u16* Prow = (u16*)(S + zoff) + (long)q * 2048;
  const int tid = threadIdx.x;
  const int ncol = q + 1;

  float v[4];
  float m = -3.4e38f;
#pragma unroll
  for (int i = 0; i < 4; ++i) {
    const int c = tid + (i << 8);
    v[i] = (c < ncol) ? Srow[c] : -3.4e38f;
    m = fmaxf(m, v[i]);
  }
#pragma unroll
  for (int off = 32; off > 0; off >>= 1) m = fmaxf(m, __shfl_xor(m, off));
  __shared__ float red[8];
  const int w = tid >> 6;
  if ((tid & 63) == 0) red[w] = m;
  __syncthreads();
  m = fmaxf(fmaxf(red[0], red[1]), fmaxf(red[2], red[3]));

  float s = 0.0f, e[4];
#pragma unroll
  for (int i = 0; i < 4; ++i) {
    const int c = tid + (i << 8);
    e[i] = (c < ncol) ? __expf(v[i] - m) : 0.0f;
    s += e[i];
  }
#pragma unroll
  for (int off = 32; off > 0; off >>= 1) s += __shfl_xor(s, off);
  if ((tid & 63) == 0) red[4 + w] = s;
  __syncthreads();
  s = red[4] + red[5] + red[6] + red[7];
  const float inv = 1.0f / s;
  const int nzend = ((q >> 7) + 1) << 7;
#pragma unroll
  for (int i = 0; i < 4; ++i) {
    const int c = tid + (i << 8);
    if (c < ncol) Prow[c] = f2b(e[i] * inv);
    else if (c < nzend) Prow[c] = 0;
  }
}

extern "C" void kernel_launch(void* const* d_in, const int* in_sizes, int n_in,
                              void* d_out, int out_size, void* d_ws, size_t ws_size,
                              hipStream_t stream) {
  const float* x   = (const float*)d_in[0];
  const float* w_k = (const float*)d_in[1];
  const float* w_q = (const float*)d_in[2];
  const float* w_v = (const float*)d_in[3];
  const float* w_u = (const float*)d_in[4];
  const float* b_u = (const float*)d_in[5];
  float* out = (float*)d_out;
  char* ws = (char*)d_ws;

  const long MB = 1048576;
  // ws layout (bytes): bf16 inputs 0..20MB, Q 20..52, K 52..84, V 84..116, O 116..148, S fp32 @148
  u16* xb  = (u16*)(ws);
  u16* wkb = (u16*)(ws + 4 * MB);
  u16* wqb = (u16*)(ws + 8 * MB);
  u16* wvb = (u16*)(ws + 12 * MB);
  u16* wub = (u16*)(ws + 16 * MB);
  u16* Q   = (u16*)(ws + 20 * MB);
  u16* Kb  = (u16*)(ws + 52 * MB);
  u16* V   = (u16*)(ws + 84 * MB);
  u16* O   = (u16*)(ws + 116 * MB);
  float* S = (float*)(ws + 148 * MB);

  // attention group size (bh per pass), by available scratch for S (G*4MB at +148MB)
  int G;
  if (ws_size >= (size_t)(276 * MB)) G = 32;      // full
  else if (ws_size >= (size_t)(180 * MB)) G = 8;  // per-batch
  else G = 1;                                     // per-(b,h)

  const dim3 blk(256);
  const float s2 = 0.044194173824159216f;  // 512^{-1/2} == (e^{-1/4})^2 folded into scores

  // fp32 -> bf16 conversions (each tensor is 2M elements = 524288 float4s)
  cvt_kernel<<<2048, blk, 0, stream>>>(x,   xb,  524288);
  cvt_kernel<<<2048, blk, 0, stream>>>(w_k, wkb, 524288);
  cvt_kernel<<<2048, blk, 0, stream>>>(w_q, wqb, 524288);
  cvt_kernel<<<2048, blk, 0, stream>>>(w_v, wvb, 524288);
  cvt_kernel<<<2048, blk, 0, stream>>>(w_u, wub, 524288);

  // QKV projections: (4096x512) @ (4096x512)^T -> (b,h,t,e)
  gemm_kernel<A_PLAIN, B_PLAIN, C_BF16_BHTE, false, false, false>
      <<<dim3(32, 32, 1), blk, 0, stream>>>(xb, 512, 0, wqb, 512, 0, Q, 0, 0, nullptr, 512, 1.0f);
  gemm_kernel<A_PLAIN, B_PLAIN, C_BF16_BHTE, false, false, false>
      <<<dim3(32, 32, 1), blk, 0, stream>>>(xb, 512, 0, wkb, 512, 0, Kb, 0, 0, nullptr, 512, 1.0f);
  gemm_kernel<A_PLAIN, B_PLAIN, C_BF16_BHTE, false, false, false>
      <<<dim3(32, 32, 1), blk, 0, stream>>>(xb, 512, 0, wvb, 512, 0, V, 0, 0, nullptr, 512, 1.0f);

  for (int g = 0; g < 32 / G; ++g) {
    const long off = (long)g * G * 524288;
    // scores: S = s2 * Q_bh @ K_bh^T, lower-triangular blocks only
    gemm_kernel<A_PLAIN, B_PLAIN, C_F32_PLAIN, true, false, false>
        <<<dim3(8, 8, G), blk, 0, stream>>>(Q + off, 512, 524288, Kb + off, 512, 524288,
                                            S, 1024, 1048576, nullptr, 512, s2);
    softmax_kernel<<<dim3(1024, G), blk, 0, stream>>>(S);
    // O_bh = P @ V_bh  (P bf16 in-place over S, lda=2048; V transpose-staged)
    gemm_kernel<A_PLAIN, B_TRANS, C_BF16_PLAIN, false, true, false>
        <<<dim3(4, 8, G), blk, 0, stream>>>((const u16*)S, 2048, 2097152, V + off, 512, 524288,
                                            O + off, 512, 524288, nullptr, 1024, 1.0f);
  }

  // unify: out(fp32) = O2d @ w_u^T + b_u  (A gathered from (b,h,t,e))
  gemm_kernel<A_HEADBLK, B_PLAIN, C_F32_PLAIN, false, false, true>
      <<<dim3(4, 32, 1), blk, 0, stream>>>(O, 0, 0, wub, 4096, 0, out, 512, 0, b_u, 4096, 1.0f);
}

// Round 3
// 449.597 us; speedup vs baseline: 1.0958x; 1.0958x over previous
//
// SelfAttentionWide (B=4, T=1024, E=512, H=8 wide heads) — MI355X gfx950
// Round 3: split-K unify (was 128 blocks @ 5.4% occupancy, 85us = 17% of total),
// fused cvt (1 dispatch) and fused QKV (1 dispatch, z=3). fp32 in/out, bf16 MFMA core.
// Layouts: Q/K/V/O in (b,h,t,e) bf16; scores S fp32 per (b,h); P bf16 in-place over S (lda=2048).
#include <hip/hip_runtime.h>
#include <stdint.h>

typedef unsigned short u16;
typedef unsigned int u32;
typedef __bf16 bf16_t;
typedef __attribute__((ext_vector_type(8))) bf16_t bf16x8;
typedef __attribute__((ext_vector_type(4))) float floatx4;

__device__ __forceinline__ u16 f2b(float f) {
  u32 u = __float_as_uint(f);
  return (u16)((u + 0x7fffu + ((u >> 16) & 1u)) >> 16);
}

// async 16B/lane global->LDS; LDS dest is wave-uniform base + lane*16
__device__ __forceinline__ void gload_lds16(const u16* g, u16* l) {
  __builtin_amdgcn_global_load_lds(
      (const __attribute__((address_space(1))) u32*)g,
      (__attribute__((address_space(3))) u32*)l, 16, 0, 0);
}

// fused fp32 -> bf16: blockIdx.y selects tensor (all 2M elements)
__global__ __launch_bounds__(256) void cvt_kernel(
    const float* __restrict__ s0, const float* __restrict__ s1,
    const float* __restrict__ s2, const float* __restrict__ s3,
    const float* __restrict__ s4, u16* __restrict__ dbase) {
  const int which = blockIdx.y;
  const float* s = which == 0 ? s0 : which == 1 ? s1 : which == 2 ? s2
                 : which == 3 ? s3 : s4;
  u16* d = dbase + (long)which * 2097152;
  const int i = blockIdx.x * 256 + threadIdx.x;
  const float4 v = ((const float4*)s)[i];
  ushort4 o;
  o.x = f2b(v.x); o.y = f2b(v.y); o.z = f2b(v.z); o.w = f2b(v.w);
  ((ushort4*)d)[i] = o;
}

// out[4096 x 512] fp32 <- broadcast bias rows (pre-pass for split-K atomic unify)
__global__ __launch_bounds__(256) void init_out_kernel(float* __restrict__ out,
                                                       const float* __restrict__ bias) {
  const int i = blockIdx.x * 256 + threadIdx.x;  // 524288 float4s
  const int c4 = i & 127;
  ((float4*)out)[i] = ((const float4*)bias)[c4];
}

enum { A_PLAIN = 0, A_HEADBLK = 1 };   // HEADBLK: A is O in (b,h,t,e), logical (r=(b,t), k=(h,e))
enum { B_PLAIN = 0, B_TRANS = 1 };     // TRANS: B global is (k,n) row-major (V), stage transposed
enum { C_BF16_PLAIN = 0, C_BF16_BHTE = 1, C_F32_PLAIN = 2, C_F32_ATOMIC = 3 };

// C[M x N] = A[M x K] @ B[N x K]^T  (bf16 in, fp32 acc), tile 128x128x32,
// 256 thr = 4 waves (2x2), wave = 4x4 of 16x16x32 MFMA.
// SPLITK: blockIdx.z selects a K-chunk of size K (param = chunk), epilogue atomics.
template <int AMODE, int BMODE, int CMODE, bool CAUSAL_SKIP, bool PV_KLIM, bool HAS_BIAS,
          bool SPLITK>
__global__ __launch_bounds__(256, 2) void gemm_kernel(
    const u16* __restrict__ A, int lda, long a_zstride,
    const u16* __restrict__ B, int ldb, long b_zstride,
    void* __restrict__ C, int ldc, long c_zstride,
    const float* __restrict__ bias, int K, float scale) {
  const int bn = blockIdx.x, bm = blockIdx.y, bz = blockIdx.z;
  if (CAUSAL_SKIP && bn > bm) return;

  int kTiles = K >> 5;
  if (PV_KLIM) kTiles = (bm + 1) * 4;  // rows q in [bm*128,+128) only need k < (bm+1)*128
  const int kbase = SPLITK ? bz * K : 0;

  const u16* Ab = A + (SPLITK ? 0 : (long)bz * a_zstride);
  const u16* Bb = B + (SPLITK ? 0 : (long)bz * b_zstride);

  constexpr int BSTR = (BMODE == B_TRANS) ? 40 : 32;  // pad to 40 (80B, 16B-mult) vs conflicts
  __shared__ u16 sA[128 * 32];
  __shared__ u16 sB[128 * BSTR];

  const int tid = threadIdx.x;
  const int wid = tid >> 6;
  const int lane = tid & 63;
  const int lrow = lane & 15;
  const int quad = lane >> 4;
  const int wm = wid >> 1, wn = wid & 1;
  const int m0 = bm * 128, n0 = bn * 128;

  const int sgr = lane >> 2;        // staging row within 16-row chunk
  const int sgc = (lane & 3) << 3;  // staging col (8 bf16 = 16B)

  floatx4 acc[4][4];
#pragma unroll
  for (int i = 0; i < 4; ++i)
#pragma unroll
    for (int j = 0; j < 4; ++j) acc[i][j] = (floatx4)0.0f;

  for (int kt = 0; kt < kTiles; ++kt) {
    const int k0 = kbase + (kt << 5);
    // ---- stage A tile (async, 16B/lane): wave wid covers rows [wid*32, wid*32+32)
#pragma unroll
    for (int j = 0; j < 2; ++j) {
      const int r = wid * 32 + j * 16 + sgr;
      const u16* g;
      if constexpr (AMODE == A_PLAIN) {
        g = Ab + (long)(m0 + r) * lda + (k0 + sgc);
      } else {
        const int rg = m0 + r, kg = k0 + sgc;
        g = Ab + (long)((rg >> 10) * 8 + (kg >> 9)) * 524288 +
            (long)(rg & 1023) * 512 + (kg & 511);
      }
      gload_lds16(g, &sA[(wid * 32 + j * 16) * 32]);
    }
    // ---- stage B tile
    if constexpr (BMODE == B_PLAIN) {
#pragma unroll
      for (int j = 0; j < 2; ++j) {
        const int r = wid * 32 + j * 16 + sgr;
        const u16* g = Bb + (long)(n0 + r) * ldb + (k0 + sgc);
        gload_lds16(g, &sB[(wid * 32 + j * 16) * 32]);
      }
    } else {
      // transpose-stage V chunk: global (k0+tr, n0+te..te+15) -> sB[n][k]
      const int tr = tid & 31, te = (tid >> 5) << 4;
      const u16* g = Bb + (long)(k0 + tr) * ldb + (n0 + te);
      union { uint4 v[2]; u16 s[16]; } tmp;
      tmp.v[0] = *(const uint4*)g;
      tmp.v[1] = *(const uint4*)(g + 8);
#pragma unroll
      for (int i = 0; i < 16; ++i) sB[(te + i) * BSTR + tr] = tmp.s[i];
    }
    __syncthreads();

    bf16x8 af[4], bfr[4];
#pragma unroll
    for (int i = 0; i < 4; ++i)
      af[i] = *(const bf16x8*)&sA[(wm * 64 + i * 16 + lrow) * 32 + (quad << 3)];
#pragma unroll
    for (int i = 0; i < 4; ++i)
      bfr[i] = *(const bf16x8*)&sB[(wn * 64 + i * 16 + lrow) * BSTR + (quad << 3)];
#pragma unroll
    for (int mi = 0; mi < 4; ++mi)
#pragma unroll
      for (int ni = 0; ni < 4; ++ni)
        acc[mi][ni] = __builtin_amdgcn_mfma_f32_16x16x32_bf16(af[mi], bfr[ni], acc[mi][ni], 0, 0, 0);
    __syncthreads();
  }

  // ---- epilogue: D[row=(quad*4+r)][col=lrow] per 16x16 tile (m89-verified layout)
#pragma unroll
  for (int mi = 0; mi < 4; ++mi) {
#pragma unroll
    for (int ni = 0; ni < 4; ++ni) {
      const int cg = n0 + wn * 64 + ni * 16 + lrow;
      float bv = 0.0f;
      if constexpr (HAS_BIAS) bv = bias[cg];
#pragma unroll
      for (int r = 0; r < 4; ++r) {
        const int rg = m0 + wm * 64 + mi * 16 + quad * 4 + r;
        const float val = acc[mi][ni][r] * scale + bv;
        if constexpr (CMODE == C_F32_PLAIN) {
          ((float*)C)[(long)bz * c_zstride + (long)rg * ldc + cg] = val;
        } else if constexpr (CMODE == C_F32_ATOMIC) {
          atomicAdd(&((float*)C)[(long)rg * ldc + cg], val);
        } else if constexpr (CMODE == C_BF16_PLAIN) {
          ((u16*)C)[(long)bz * c_zstride + (long)rg * ldc + cg] = f2b(val);
        } else {  // C_BF16_BHTE: (r=(b,t), c=(h,e)) -> (b,h,t,e), + z offset
          const long idx = (long)bz * c_zstride +
                           (long)((rg >> 10) * 8 + (cg >> 9)) * 524288 +
                           (long)(rg & 1023) * 512 + (cg & 511);
          ((u16*)C)[idx] = f2b(val);
        }
      }
    }
  }
}

// causal row softmax over S fp32 row q (cols 0..q), write P bf16 in place (lda=2048),
// zero-fill P cols q+1 .. round_up_128(q+1) so the PV GEMM can read full k-tiles.
__global__ __launch_bounds__(256) void softmax_kernel(float* __restrict__ S) {
  const int q = blockIdx.x;
  const long zoff = (long)blockIdx.y * 1048576;
  const float* Srow = S + zoff + (long)q * 1024;
  u16* Prow = (u16*)(S + zoff) + (long)q * 2048;
  const int tid = threadIdx.x;
  const int ncol = q + 1;

  float v[4];
  float m = -3.4e38f;
#pragma unroll
  for (int i = 0; i < 4; ++i) {
    const int c = tid + (i << 8);
    v[i] = (c < ncol) ? Srow[c] : -3.4e38f;
    m = fmaxf(m, v[i]);
  }
#pragma unroll
  for (int off = 32; off > 0; off >>= 1) m = fmaxf(m, __shfl_xor(m, off));
  __shared__ float red[8];
  const int w = tid >> 6;
  if ((tid & 63) == 0) red[w] = m;
  __syncthreads();
  m = fmaxf(fmaxf(red[0], red[1]), fmaxf(red[2], red[3]));

  float s = 0.0f, e[4];
#pragma unroll
  for (int i = 0; i < 4; ++i) {
    const int c = tid + (i << 8);
    e[i] = (c < ncol) ? __expf(v[i] - m) : 0.0f;
    s += e[i];
  }
#pragma unroll
  for (int off = 32; off > 0; off >>= 1) s += __shfl_xor(s, off);
  if ((tid & 63) == 0) red[4 + w] = s;
  __syncthreads();
  s = red[4] + red[5] + red[6] + red[7];
  const float inv = 1.0f / s;
  const int nzend = ((q >> 7) + 1) << 7;
#pragma unroll
  for (int i = 0; i < 4; ++i) {
    const int c = tid + (i << 8);
    if (c < ncol) Prow[c] = f2b(e[i] * inv);
    else if (c < nzend) Prow[c] = 0;
  }
}

extern "C" void kernel_launch(void* const* d_in, const int* in_sizes, int n_in,
                              void* d_out, int out_size, void* d_ws, size_t ws_size,
                              hipStream_t stream) {
  const float* x   = (const float*)d_in[0];
  const float* w_k = (const float*)d_in[1];
  const float* w_q = (const float*)d_in[2];
  const float* w_v = (const float*)d_in[3];
  const float* w_u = (const float*)d_in[4];
  const float* b_u = (const float*)d_in[5];
  float* out = (float*)d_out;
  char* ws = (char*)d_ws;

  const long MB = 1048576;
  // ws layout (bytes): xb 0, wqb 4, wkb 8, wvb 12, wub 16 (bf16, contiguous q/k/v for z-fused
  // QKV gemm); Q 20..52, K 52..84, V 84..116, O 116..148, S fp32 @148
  u16* xb  = (u16*)(ws);
  u16* wqb = (u16*)(ws + 4 * MB);
  u16* wub = (u16*)(ws + 16 * MB);
  u16* Q   = (u16*)(ws + 20 * MB);
  u16* Kb  = (u16*)(ws + 52 * MB);
  u16* V   = (u16*)(ws + 84 * MB);
  u16* O   = (u16*)(ws + 116 * MB);
  float* S = (float*)(ws + 148 * MB);

  // attention group size (bh per pass), by available scratch for S (G*4MB at +148MB)
  int G;
  if (ws_size >= (size_t)(282 * MB)) G = 32;      // full
  else if (ws_size >= (size_t)(180 * MB)) G = 8;  // per-batch
  else G = 1;                                     // per-(b,h)

  const dim3 blk(256);
  const float s2 = 0.044194173824159216f;  // 512^{-1/2} == (e^{-1/4})^2 folded into scores

  // fused fp32 -> bf16 conversions: dest order matches ws layout (x,q,k,v,u)
  cvt_kernel<<<dim3(2048, 5), blk, 0, stream>>>(x, w_q, w_k, w_v, w_u, xb);

  // fused QKV projections, z in {q,k,v}: (4096x512) @ (4096x512)^T -> (b,h,t,e)
  // b_zstride = 4MB/2 elems (wqb->wkb->wvb), c_zstride = 32MB/2 elems (Q->K->V)
  gemm_kernel<A_PLAIN, B_PLAIN, C_BF16_BHTE, false, false, false, false>
      <<<dim3(32, 32, 3), blk, 0, stream>>>(xb, 512, 0, wqb, 512, 2097152,
                                            Q, 0, 16777216, nullptr, 512, 1.0f);

  for (int g = 0; g < 32 / G; ++g) {
    const long off = (long)g * G * 524288;
    // scores: S = s2 * Q_bh @ K_bh^T, lower-triangular blocks only
    gemm_kernel<A_PLAIN, B_PLAIN, C_F32_PLAIN, true, false, false, false>
        <<<dim3(8, 8, G), blk, 0, stream>>>(Q + off, 512, 524288, Kb + off, 512, 524288,
                                            S, 1024, 1048576, nullptr, 512, s2);
    softmax_kernel<<<dim3(1024, G), blk, 0, stream>>>(S);
    // O_bh = P @ V_bh  (P bf16 in-place over S, lda=2048; V transpose-staged)
    gemm_kernel<A_PLAIN, B_TRANS, C_BF16_PLAIN, false, true, false, false>
        <<<dim3(4, 8, G), blk, 0, stream>>>((const u16*)S, 2048, 2097152, V + off, 512, 524288,
                                            O + off, 512, 524288, nullptr, 1024, 1.0f);
  }

  // unify: out(fp32) = O2d @ w_u^T + b_u, split-K x4 (K-chunk 1024) for occupancy:
  // grid 4x32x4 = 512 blocks (was 128 @ 5.4% occupancy). Bias via init, partials via atomicAdd.
  init_out_kernel<<<2048, blk, 0, stream>>>(out, b_u);
  gemm_kernel<A_HEADBLK, B_PLAIN, C_F32_ATOMIC, false, false, false, true>
      <<<dim3(4, 32, 4), blk, 0, stream>>>(O, 0, 0, wub, 4096, 0, out, 512, 0,
                                           nullptr, 1024, 1.0f);
}